// Round 7
// baseline (455.695 us; speedup 1.0000x reference)
//
#include <hip/hip_runtime.h>
#include <hip/hip_bf16.h>
#include <math.h>

#define LN_EPS 1e-5f

typedef short short8 __attribute__((ext_vector_type(8)));
typedef float floatx4 __attribute__((ext_vector_type(4)));

__device__ inline unsigned short f2bf(float f) {
    unsigned int u = __float_as_uint(f);
    u += 0x7fff + ((u >> 16) & 1);   // round-to-nearest-even
    return (unsigned short)(u >> 16);
}

__device__ inline void gl_lds16(const unsigned short* g, unsigned short* l) {
    __builtin_amdgcn_global_load_lds(
        (__attribute__((address_space(1))) const void*)g,
        (__attribute__((address_space(3))) void*)l, 16, 0, 0);
}

// overflow-safe tanh-approx GELU (max abs err ~1e-3 vs exact)
__device__ inline float gelu_f(float v) {
    float u2 = 2.0f * v * (0.7978845608f + 0.0356774081f * v * v);
    float t  = 1.0f - 2.0f / (__expf(u2) + 1.0f);
    return 0.5f * v * (1.0f + t);
}

#define CFENCE asm volatile("" ::: "memory")

// ---------------------------------------------------------------------------
// 256xBN bf16 MFMA GEMM (r4-measured-best schedule; r5 split-K and r6 deep
// staging both failed their predictions and are reverted).
//  A: MxK row-major bf16.  B: NxK row-major bf16 (B^T given).
//  BM=256, BK=64, 512 threads = 8 waves (2M x 4N). Per-wave out 128 x BN/4.
//  LDS per matrix: [2 dbuf][2 kh][rows][32 elems] (64B rows), double-buffered.
//  T1: bijective XCD-chunk swizzle — blocks sharing an A-panel land on the
//      same XCD L2 (fetch 282->82MB on PV gemm, r2). nwg mult of 8 always.
//  T2: st_16x32 swizzle — linear global_load_lds dest, source k-chunk XOR'd
//      by (row&8)?2:0, ds_read applies the same XOR. (rule #21: both sides)
//  T3/T4: counted vmcnt at the K-tile boundary only — never 0 mid-loop.
//  T5: setprio(1) around each MFMA cluster.
//  BN=256: 4 phases/K-tile, 16-MFMA clusters, vmcnt(4) (FFN1: 93.0 µs,
//      739 TF = 87% of m248's shape-matched 848 TF reference; r6's deeper
//      vmcnt(6) staging measured NEUTRAL-negative -> reverted).
//  BN=128: 2 phases/K-tile, 16-MFMA clusters, vmcnt(2) (r4 fix; ~500 TF).
//  GRID CHOICE (r7): for N=1024, K-large GEMMs (FFN2, K=4096) run BN=256
//      on 128 blocks (HALF machine) — per-block rate ~6.1 GF/us (m201-class
//      at nt=64) vs BN=128's ~1.95 at full machine: 537MF/6.1 = 88 µs beats
//      268MF/1.95 = 137 µs. Per-block efficiency dominates occupancy.
//      PV (K=2048, mid-regime) stays BN=128 (arithmetic is a wash).
//  Swapped-operand MFMA: mfma(bfr, afr) -> lane holds row(l16) x 4 cols(quad).
//  EPI: 2 = +bias, GELU, bf16 out
//       3 = *scale + mask[batch][col], bf16 out       (QK^T scores)
//       4 = +resid[batch], fp32 out                   (PV: x + attn)
//       5 = +bias +resid, fp32 out                    (FFN2: h + ffn)
//  M mult of 256; N mult of BN; K mult of 128.
// ---------------------------------------------------------------------------
template<int EPI, int BN>
__global__ __launch_bounds__(512, 2) void gemm8p(
    const unsigned short* __restrict__ A, const unsigned short* __restrict__ B,
    const float* __restrict__ bias, const float* __restrict__ resid,
    void* __restrict__ Cptr,
    int M, int N, int K, long sA, long sB, long sC, long sBias, float scale)
{
    static_assert(BN == 256 || BN == 128, "BN must be 256 or 128");
    constexpr int WC = BN / 4;    // per-wave col span: 64 or 32
    constexpr int NT = WC / 16;   // n-tiles per wave: 4 or 2
    constexpr int NH = NT / 2;    // n-tiles per half-group: 2 or 1

    __shared__ alignas(16) unsigned short lds_a[2][2][256 * 32]; // 64 KB
    __shared__ alignas(16) unsigned short lds_b[2][2][BN * 32];  // 64/32 KB

    const int tid  = threadIdx.x;
    const int lane = tid & 63;
    const int wave = tid >> 6;         // 0..7
    const int quad = lane >> 4;
    const int l16  = lane & 15;
    const int wm = wave >> 2;          // 0..1  (128-row half)
    const int wn = wave & 3;           // 0..3  (WC-col slice)

    // ---- T1: XCD-chunk swizzle (nwg % 8 == 0 for all our grids) ----
    const int nwg = gridDim.x * gridDim.y * gridDim.z;
    int lin = blockIdx.x + gridDim.x * (blockIdx.y + gridDim.y * blockIdx.z);
    if ((nwg & 7) == 0) lin = (lin & 7) * (nwg >> 3) + (lin >> 3);
    const int bx = lin % gridDim.x;
    const int byz = lin / gridDim.x;
    const int by = byz % gridDim.y;
    const int bz = byz / gridDim.y;

    const int tile_m = by * 256;
    const int tile_n = bx * BN;
    const int batch  = bz;

    const unsigned short* Ab = A + (size_t)batch * sA;
    const unsigned short* Bb = B + (size_t)batch * sB;

    // staging: 512 threads x 16B = 8KB/inst = one [128 rows][32 elems] region.
    // LDS dest linear (tid*16B); global source k-chunk pre-swizzled.
    const int srow = tid >> 2;                                  // 0..127
    const int scs  = ((tid & 3) ^ ((tid & 32) ? 2 : 0)) * 8;    // swz chunk
    const unsigned short* gA = Ab + (size_t)(tile_m + srow) * K + scs;
    const unsigned short* gB = Bb + (size_t)(tile_n + srow) * K + scs;
    const int ldst = tid * 8;                                   // elems

    // fragment reads: row = (wm*128|wn*WC) + tile*16 + l16; row&8 == l16&8
    const int kcs   = (quad * 8) ^ ((l16 & 8) << 1);            // swz k-off
    const int abase = (wm * 128 + l16) * 32 + kcs;
    const int bbase = (wn * WC  + l16) * 32 + kcs;

    floatx4 acc[8][NT];
    const floatx4 zero = {0.f, 0.f, 0.f, 0.f};
#pragma unroll
    for (int i = 0; i < 8; i++)
#pragma unroll
        for (int j = 0; j < NT; j++) acc[i][j] = zero;

    auto stageA = [&](int buf, int h, int k0) {   // h = 128-row half
        const unsigned short* s = gA + (size_t)h * 128 * K + k0;
        gl_lds16(s,      &lds_a[buf][0][h * 4096 + ldst]);
        gl_lds16(s + 32, &lds_a[buf][1][h * 4096 + ldst]);
    };
    auto stageB = [&](int buf, int h, int k0) {
        const unsigned short* s = gB + (size_t)h * 128 * K + k0;
        gl_lds16(s,      &lds_b[buf][0][h * 4096 + ldst]);
        gl_lds16(s + 32, &lds_b[buf][1][h * 4096 + ldst]);
    };

    const int nt = K >> 6;

    // ---- prologue: tile0 fully + tile1's B (steady-state invariant) ----
    stageA(0, 0, 0); stageA(0, 1, 0);
    stageB(0, 0, 0);
    if constexpr (BN == 256) stageB(0, 1, 0);
    if (nt > 1) {
        stageB(1, 0, 64);
        if constexpr (BN == 256) stageB(1, 1, 64);
        if constexpr (BN == 256) { asm volatile("s_waitcnt vmcnt(4)" ::: "memory"); }
        else                     { asm volatile("s_waitcnt vmcnt(2)" ::: "memory"); }
    } else {
        asm volatile("s_waitcnt vmcnt(0)" ::: "memory");
    }
    __builtin_amdgcn_s_barrier(); CFENCE;

    int cur = 0;

    if constexpr (BN == 128) {
        // ================= 2-phase loop, 16-MFMA clusters =================
        for (int t = 0; t < nt; ++t) {
            const int k0 = t * 64;
            short8 afr[4][2], bfr[2][2];

            // ---- P1: read A rows q1 + ALL B ; stage A(t+1) ----
#pragma unroll
            for (int i = 0; i < 4; i++)
#pragma unroll
                for (int kh = 0; kh < 2; kh++)
                    afr[i][kh] = *(const short8*)&lds_a[cur][kh][abase + i * 512];
#pragma unroll
            for (int j = 0; j < 2; j++)
#pragma unroll
                for (int kh = 0; kh < 2; kh++)
                    bfr[j][kh] = *(const short8*)&lds_b[cur][kh][bbase + j * 512];
            if (t + 1 < nt) { stageA(cur ^ 1, 0, k0 + 64); stageA(cur ^ 1, 1, k0 + 64); }
            CFENCE; __builtin_amdgcn_s_barrier(); CFENCE;
            __builtin_amdgcn_s_setprio(1);
#pragma unroll
            for (int i = 0; i < 4; i++)
#pragma unroll
                for (int j = 0; j < 2; j++)
#pragma unroll
                    for (int kh = 0; kh < 2; kh++)
                        acc[i][j] = __builtin_amdgcn_mfma_f32_16x16x32_bf16(
                            bfr[j][kh], afr[i][kh], acc[i][j], 0, 0, 0);
            __builtin_amdgcn_s_setprio(0);
            // end-P1 barrier: all waves' B reads complete -> B buf half dead
            CFENCE; __builtin_amdgcn_s_barrier(); CFENCE;

            // ---- P2: read A rows q2 ; stage B(t+2) over dead half ----
#pragma unroll
            for (int i = 0; i < 4; i++)
#pragma unroll
                for (int kh = 0; kh < 2; kh++)
                    afr[i][kh] = *(const short8*)&lds_a[cur][kh][abase + (4 + i) * 512];
            if (t + 2 < nt) stageB(cur, 0, k0 + 128);
            __builtin_amdgcn_s_setprio(1);
#pragma unroll
            for (int i = 0; i < 4; i++)
#pragma unroll
                for (int j = 0; j < 2; j++)
#pragma unroll
                    for (int kh = 0; kh < 2; kh++)
                        acc[4 + i][j] = __builtin_amdgcn_mfma_f32_16x16x32_bf16(
                            bfr[j][kh], afr[i][kh], acc[4 + i][j], 0, 0, 0);
            __builtin_amdgcn_s_setprio(0);
            // K-tile boundary: outstanding = A(t+1)x4 + B(t+2)x2 -> vmcnt(2)
            if (t + 3 <= nt) {
                asm volatile("s_waitcnt vmcnt(2)" ::: "memory");
                __builtin_amdgcn_s_barrier(); CFENCE;
            } else if (t + 2 == nt) {
                asm volatile("s_waitcnt vmcnt(0)" ::: "memory");
                __builtin_amdgcn_s_barrier(); CFENCE;
            }
            cur ^= 1;
        }
    } else {
        // ================= 4-phase loop (r4 shallow staging) =================
        for (int t = 0; t < nt; ++t) {
            const int k0 = t * 64;
            short8 afr[4][2], bfrA[NH][2], bfrB[NH][2];

            // ========== P1: read A0 + B0 ; stage A(t+1, lo) ==========
#pragma unroll
            for (int i = 0; i < 4; i++)
#pragma unroll
                for (int kh = 0; kh < 2; kh++)
                    afr[i][kh] = *(const short8*)&lds_a[cur][kh][abase + i * 512];
#pragma unroll
            for (int j = 0; j < NH; j++)
#pragma unroll
                for (int kh = 0; kh < 2; kh++)
                    bfrA[j][kh] = *(const short8*)&lds_b[cur][kh][bbase + j * 512];
            if (t + 1 < nt) stageA(cur ^ 1, 0, k0 + 64);
            CFENCE; __builtin_amdgcn_s_barrier(); CFENCE;
            __builtin_amdgcn_s_setprio(1);
#pragma unroll
            for (int i = 0; i < 4; i++)
#pragma unroll
                for (int j = 0; j < NH; j++)
#pragma unroll
                    for (int kh = 0; kh < 2; kh++)
                        acc[i][j] = __builtin_amdgcn_mfma_f32_16x16x32_bf16(
                            bfrA[j][kh], afr[i][kh], acc[i][j], 0, 0, 0);
            __builtin_amdgcn_s_setprio(0);
            CFENCE; __builtin_amdgcn_s_barrier(); CFENCE;

            // ========== P2: read B1 ; stage A(t+1, hi) ==========
#pragma unroll
            for (int j = 0; j < NH; j++)
#pragma unroll
                for (int kh = 0; kh < 2; kh++)
                    bfrB[j][kh] = *(const short8*)&lds_b[cur][kh][bbase + (NH + j) * 512];
            if (t + 1 < nt) stageA(cur ^ 1, 1, k0 + 64);
            CFENCE; __builtin_amdgcn_s_barrier(); CFENCE;
            __builtin_amdgcn_s_setprio(1);
#pragma unroll
            for (int i = 0; i < 4; i++)
#pragma unroll
                for (int j = 0; j < NH; j++)
#pragma unroll
                    for (int kh = 0; kh < 2; kh++)
                        acc[i][NH + j] = __builtin_amdgcn_mfma_f32_16x16x32_bf16(
                            bfrB[j][kh], afr[i][kh], acc[i][NH + j], 0, 0, 0);
            __builtin_amdgcn_s_setprio(0);
            CFENCE; __builtin_amdgcn_s_barrier(); CFENCE;

            // ========== P3: read A1 ; stage B(t+2, lo) ==========
#pragma unroll
            for (int i = 0; i < 4; i++)
#pragma unroll
                for (int kh = 0; kh < 2; kh++)
                    afr[i][kh] = *(const short8*)&lds_a[cur][kh][abase + (4 + i) * 512];
            if (t + 2 < nt) stageB(cur, 0, k0 + 128);
            CFENCE; __builtin_amdgcn_s_barrier(); CFENCE;
            __builtin_amdgcn_s_setprio(1);
#pragma unroll
            for (int i = 0; i < 4; i++)
#pragma unroll
                for (int j = 0; j < NH; j++)
#pragma unroll
                    for (int kh = 0; kh < 2; kh++)
                        acc[4 + i][NH + j] = __builtin_amdgcn_mfma_f32_16x16x32_bf16(
                            bfrB[j][kh], afr[i][kh], acc[4 + i][NH + j], 0, 0, 0);
            __builtin_amdgcn_s_setprio(0);
            CFENCE; __builtin_amdgcn_s_barrier(); CFENCE;

            // ========== P4: stage B(t+2, hi) ; MFMA from regs ; boundary ==
            if (t + 2 < nt) stageB(cur, 1, k0 + 128);
            __builtin_amdgcn_s_setprio(1);
#pragma unroll
            for (int i = 0; i < 4; i++)
#pragma unroll
                for (int j = 0; j < NH; j++)
#pragma unroll
                    for (int kh = 0; kh < 2; kh++)
                        acc[4 + i][j] = __builtin_amdgcn_mfma_f32_16x16x32_bf16(
                            bfrA[j][kh], afr[i][kh], acc[4 + i][j], 0, 0, 0);
            __builtin_amdgcn_s_setprio(0);
            if (t + 3 <= nt) {
                asm volatile("s_waitcnt vmcnt(4)" ::: "memory");
                __builtin_amdgcn_s_barrier(); CFENCE;
            } else if (t + 2 == nt) {
                asm volatile("s_waitcnt vmcnt(0)" ::: "memory");
                __builtin_amdgcn_s_barrier(); CFENCE;
            }
            cur ^= 1;
        }
    }

    // ---- epilogue: per frag, lane holds row (l16) x 4 consecutive cols ----
#pragma unroll
    for (int i = 0; i < 8; i++) {
        const int row = tile_m + wm * 128 + i * 16 + l16;
#pragma unroll
        for (int j = 0; j < NT; j++) {
            const int colb = tile_n + wn * WC + j * 16 + quad * 4;
            float v[4];
#pragma unroll
            for (int r = 0; r < 4; r++) v[r] = acc[i][j][r];

            if (EPI == 3) {
                float4 mv = *(const float4*)&bias[(size_t)batch * sBias + colb];
                v[0] = v[0] * scale + mv.x;  v[1] = v[1] * scale + mv.y;
                v[2] = v[2] * scale + mv.z;  v[3] = v[3] * scale + mv.w;
            }
            if (EPI == 2 || EPI == 5) {
                float4 bv = *(const float4*)&bias[colb];
                v[0] += bv.x; v[1] += bv.y; v[2] += bv.z; v[3] += bv.w;
            }
            if (EPI == 2) {
#pragma unroll
                for (int r = 0; r < 4; r++) v[r] = gelu_f(v[r]);
            }
            if (EPI == 4 || EPI == 5) {
                float4 rv = *(const float4*)&resid[(size_t)batch * sC +
                                                   (size_t)row * N + colb];
                v[0] += rv.x; v[1] += rv.y; v[2] += rv.z; v[3] += rv.w;
            }

            if (EPI == 2 || EPI == 3) {
                unsigned short* C = (unsigned short*)Cptr + (size_t)batch * sC;
                ushort4 h4;
                h4.x = f2bf(v[0]); h4.y = f2bf(v[1]);
                h4.z = f2bf(v[2]); h4.w = f2bf(v[3]);
                *(ushort4*)(C + (size_t)row * N + colb) = h4;
            } else {
                float* C = (float*)Cptr + (size_t)batch * sC;
                float4 f4 = {v[0], v[1], v[2], v[3]};
                *(float4*)(C + (size_t)row * N + colb) = f4;
            }
        }
    }
}

// ---------------------------------------------------------------------------
// x prep: read x [S,D] fp32 once -> xb [S,D] bf16 AND xTb [D,S] bf16.
// ---------------------------------------------------------------------------
__global__ __launch_bounds__(256) void x_prep_kernel(
    const float* __restrict__ in, unsigned short* __restrict__ straight,
    unsigned short* __restrict__ transposed, int R, int C, long sIn)
{
    __shared__ float tile[32][33];
    const int tc = blockIdx.x * 32, tr = blockIdx.y * 32;
    const float* src = in + (size_t)blockIdx.z * sIn;
    unsigned short* dstS = straight   + (size_t)blockIdx.z * sIn;
    unsigned short* dstT = transposed + (size_t)blockIdx.z * sIn;
    const int tx = threadIdx.x & 31, ty = threadIdx.x >> 5;
#pragma unroll
    for (int i = 0; i < 4; i++) {
        float val = src[(size_t)(tr + ty + i * 8) * C + tc + tx];
        tile[ty + i * 8][tx] = val;
        dstS[(size_t)(tr + ty + i * 8) * C + tc + tx] = f2bf(val);
    }
    __syncthreads();
#pragma unroll
    for (int i = 0; i < 4; i++)
        dstT[(size_t)(tc + ty + i * 8) * R + tr + tx] = f2bf(tile[tx][ty + i * 8]);
}

// ---------------------------------------------------------------------------
__global__ __launch_bounds__(256) void transpose_cvt_kernel(
    const float* __restrict__ in, unsigned short* __restrict__ out, int R, int C)
{
    __shared__ float tile[32][33];
    const int tc = blockIdx.x * 32, tr = blockIdx.y * 32;
    const int tx = threadIdx.x & 31, ty = threadIdx.x >> 5;
#pragma unroll
    for (int i = 0; i < 4; i++)
        tile[ty + i * 8][tx] = in[(size_t)(tr + ty + i * 8) * C + tc + tx];
    __syncthreads();
#pragma unroll
    for (int i = 0; i < 4; i++)
        out[(size_t)(tc + ty + i * 8) * R + tr + tx] = f2bf(tile[tx][ty + i * 8]);
}

// ---------------------------------------------------------------------------
// Pure row softmax over S=2048: bf16 in (scale+mask pre-applied) -> bf16 out.
// ---------------------------------------------------------------------------
__global__ __launch_bounds__(256) void softmax_bf16_kernel(
    const unsigned short* __restrict__ scores, unsigned short* __restrict__ probs,
    int S)
{
    __shared__ float red[4];
    const int row = blockIdx.x;
    const unsigned short* p = scores + (size_t)row * S;
    unsigned short* pr      = probs  + (size_t)row * S;
    const int tid  = threadIdx.x;
    const int lane = tid & 63;
    const int wav  = tid >> 6;

    uint4 raw = *(const uint4*)(p + tid * 8);   // 8 bf16
    float v[8];
    v[0] = __uint_as_float(raw.x << 16); v[1] = __uint_as_float(raw.x & 0xffff0000u);
    v[2] = __uint_as_float(raw.y << 16); v[3] = __uint_as_float(raw.y & 0xffff0000u);
    v[4] = __uint_as_float(raw.z << 16); v[5] = __uint_as_float(raw.z & 0xffff0000u);
    v[6] = __uint_as_float(raw.w << 16); v[7] = __uint_as_float(raw.w & 0xffff0000u);

    float mx = v[0];
#pragma unroll
    for (int k = 1; k < 8; k++) mx = fmaxf(mx, v[k]);
#pragma unroll
    for (int off = 32; off > 0; off >>= 1) mx = fmaxf(mx, __shfl_down(mx, off));
    if (lane == 0) red[wav] = mx;
    __syncthreads();
    mx = fmaxf(fmaxf(red[0], red[1]), fmaxf(red[2], red[3]));
    __syncthreads();

    float s = 0.f;
#pragma unroll
    for (int k = 0; k < 8; k++) { v[k] = __expf(v[k] - mx); s += v[k]; }
#pragma unroll
    for (int off = 32; off > 0; off >>= 1) s += __shfl_down(s, off);
    if (lane == 0) red[wav] = s;
    __syncthreads();
    s = red[0] + red[1] + red[2] + red[3];
    float inv = 1.0f / s;

    uint4 o;
    o.x = (unsigned)f2bf(v[0] * inv) | ((unsigned)f2bf(v[1] * inv) << 16);
    o.y = (unsigned)f2bf(v[2] * inv) | ((unsigned)f2bf(v[3] * inv) << 16);
    o.z = (unsigned)f2bf(v[4] * inv) | ((unsigned)f2bf(v[5] * inv) << 16);
    o.w = (unsigned)f2bf(v[6] * inv) | ((unsigned)f2bf(v[7] * inv) << 16);
    *(uint4*)(pr + tid * 8) = o;
}

// ---------------------------------------------------------------------------
// out_row = LayerNorm(X_row)*g + b.  D = 1024. In-place safe (out == X).
// ---------------------------------------------------------------------------
template<int WRITE_BF16>
__global__ __launch_bounds__(256) void ln_kernel(
    const float* __restrict__ X,
    const float* __restrict__ g, const float* __restrict__ bta,
    float* __restrict__ out, unsigned short* __restrict__ out16, int D)
{
    __shared__ float red[8];
    const int row = blockIdx.x;
    const float* x = X + (size_t)row * D;
    const int tid  = threadIdx.x;
    const int lane = tid & 63;
    const int wav  = tid >> 6;

    float4 a = *(const float4*)(x + tid * 4);
    float v0 = a.x, v1 = a.y, v2 = a.z, v3 = a.w;

    float s1 = v0 + v1 + v2 + v3;
    float s2 = v0 * v0 + v1 * v1 + v2 * v2 + v3 * v3;
#pragma unroll
    for (int off = 32; off > 0; off >>= 1) {
        s1 += __shfl_down(s1, off);
        s2 += __shfl_down(s2, off);
    }
    if (lane == 0) { red[wav] = s1; red[4 + wav] = s2; }
    __syncthreads();
    s1 = red[0] + red[1] + red[2] + red[3];
    s2 = red[4] + red[5] + red[6] + red[7];
    const float mu  = s1 / (float)D;
    const float var = s2 / (float)D - mu * mu;
    const float rs  = rsqrtf(var + LN_EPS);

    float4 gg = *(const float4*)(g + tid * 4);
    float4 bb = *(const float4*)(bta + tid * 4);
    float4 r;
    r.x = (v0 - mu) * rs * gg.x + bb.x;
    r.y = (v1 - mu) * rs * gg.y + bb.y;
    r.z = (v2 - mu) * rs * gg.z + bb.z;
    r.w = (v3 - mu) * rs * gg.w + bb.w;
    *(float4*)(out + (size_t)row * D + tid * 4) = r;
    if (WRITE_BF16) {
        ushort4 h;
        h.x = f2bf(r.x); h.y = f2bf(r.y); h.z = f2bf(r.z); h.w = f2bf(r.w);
        *(ushort4*)(out16 + (size_t)row * D + tid * 4) = h;
    }
}

// ---------------------------------------------------------------------------
extern "C" void kernel_launch(void* const* d_in, const int* in_sizes, int n_in,
                              void* d_out, int out_size, void* d_ws, size_t ws_size,
                              hipStream_t stream) {
    (void)in_sizes; (void)n_in; (void)out_size; (void)ws_size;
    const float* x    = (const float*)d_in[0];
    const float* mask = (const float*)d_in[1];
    const float* w1   = (const float*)d_in[2];
    const float* b1   = (const float*)d_in[3];
    const float* w2   = (const float*)d_in[4];
    const float* b2   = (const float*)d_in[5];
    const float* ln1g = (const float*)d_in[6];
    const float* ln1b = (const float*)d_in[7];
    const float* ln2g = (const float*)d_in[8];
    const float* ln2b = (const float*)d_in[9];
    float* out = (float*)d_out;

    const int B = 4, S = 2048, D = 1024, DFF = 4096;
    const size_t MB = 1024 * 1024;

    // ws (128 MiB):
    //  [0,32M):   scoresb bf16 (1-2)         } act bf16 [0,64M) (5-6)
    //  [32,64M):  xb bf16 [32,48M) (prep-1), then probs bf16 (2-3)
    //  [64,96M):  hbuf fp32 = h (3-6)
    //  [96,112M): hb16 bf16 (4-5)
    //  [112,120M): w1T   [120,128M): w2T
    // d_out (32 MiB): xTb [0,16M) (prep-3); then fsum fp32 = h+ffn (6-7), LN in place.
    char* ws = (char*)d_ws;
    unsigned short* scoresb = (unsigned short*)ws;
    unsigned short* act     = (unsigned short*)ws;
    unsigned short* xb      = (unsigned short*)(ws + 32 * MB);
    unsigned short* probs   = (unsigned short*)(ws + 32 * MB);
    float*          hbuf    = (float*)(ws + 64 * MB);
    unsigned short* hb16    = (unsigned short*)(ws + 96 * MB);
    unsigned short* w1T     = (unsigned short*)(ws + 112 * MB);
    unsigned short* w2T     = (unsigned short*)(ws + 120 * MB);
    unsigned short* xTb     = (unsigned short*)d_out;
    float*          fsum    = (float*)d_out;

    // --- prep ---
    x_prep_kernel<<<dim3(D / 32, S / 32, B), 256, 0, stream>>>(
        x, xb, xTb, S, D, (long)S * D);
    transpose_cvt_kernel<<<dim3(DFF / 32, D / 32, 1), 256, 0, stream>>>(w1, w1T, D, DFF);
    transpose_cvt_kernel<<<dim3(D / 32, DFF / 32, 1), 256, 0, stream>>>(w2, w2T, DFF, D);

    // 1. scoresb[b] = (xb[b] @ xb[b]^T)*scale + mask  -> bf16   (256 blocks)
    hipLaunchKernelGGL((gemm8p<3, 256>), dim3(S / 256, S / 256, B), dim3(512), 0, stream,
                       xb, xb, mask, (const float*)nullptr, (void*)scoresb,
                       S, S, D, (long)S * D, (long)S * D, (long)S * S, (long)S, 0.03125f);
    // 2. probs = softmax(scoresb) -> bf16
    softmax_bf16_kernel<<<B * S, 256, 0, stream>>>(scoresb, probs, S);
    // 3. hbuf[b] = x[b] + probs[b] @ xTb[b]^T  -> fp32          (256 blocks)
    hipLaunchKernelGGL((gemm8p<4, 128>), dim3(D / 128, S / 256, B), dim3(512), 0, stream,
                       probs, xTb, (const float*)nullptr, x, (void*)hbuf,
                       S, D, S, (long)S * S, (long)D * S, (long)S * D, 0L, 0.f);
    // 4. h = LN(hbuf) in place + hb16 bf16
    hipLaunchKernelGGL((ln_kernel<1>), dim3(B * S), dim3(256), 0, stream,
                       hbuf, ln1g, ln1b, hbuf, hb16, D);
    // 5. act = gelu(h @ w1 + b1) -> bf16                        (512 blocks)
    hipLaunchKernelGGL((gemm8p<2, 256>), dim3(DFF / 256, (B * S) / 256, 1), dim3(512), 0, stream,
                       hb16, w1T, b1, (const float*)nullptr, (void*)act,
                       B * S, DFF, D, 0L, 0L, 0L, 0L, 0.f);
    // 6. fsum = h + act @ w2 + b2 -> fp32 (into d_out)
    //    r7: BN=256 at 128 blocks (half machine) — per-block m201-class rate
    //    at K=4096 beats BN=128 at full machine (88 vs ~130 µs predicted).
    hipLaunchKernelGGL((gemm8p<5, 256>), dim3(D / 256, (B * S) / 256, 1), dim3(512), 0, stream,
                       act, w2T, b2, hbuf, (void*)fsum,
                       B * S, D, DFF, 0L, 0L, 0L, 0L, 0.f);
    // 7. out = LN(fsum) in place
    hipLaunchKernelGGL((ln_kernel<0>), dim3(B * S), dim3(256), 0, stream,
                       fsum, ln2g, ln2b, out, (unsigned short*)nullptr, D);
}

// Round 8
// 407.076 us; speedup vs baseline: 1.1194x; 1.1194x over previous
//
#include <hip/hip_runtime.h>
#include <hip/hip_bf16.h>
#include <math.h>

#define LN_EPS 1e-5f

typedef short short8 __attribute__((ext_vector_type(8)));
typedef float floatx4 __attribute__((ext_vector_type(4)));

__device__ inline unsigned short f2bf(float f) {
    unsigned int u = __float_as_uint(f);
    u += 0x7fff + ((u >> 16) & 1);   // round-to-nearest-even
    return (unsigned short)(u >> 16);
}

__device__ inline void gl_lds16(const unsigned short* g, unsigned short* l) {
    __builtin_amdgcn_global_load_lds(
        (__attribute__((address_space(1))) const void*)g,
        (__attribute__((address_space(3))) void*)l, 16, 0, 0);
}

// overflow-safe tanh-approx GELU (max abs err ~1e-3 vs exact)
__device__ inline float gelu_f(float v) {
    float u2 = 2.0f * v * (0.7978845608f + 0.0356774081f * v * v);
    float t  = 1.0f - 2.0f / (__expf(u2) + 1.0f);
    return 0.5f * v * (1.0f + t);
}

#define CFENCE asm volatile("" ::: "memory")

// ---------------------------------------------------------------------------
// 256xBN bf16 MFMA GEMM — EXACT r4 configuration (measured best: 412.7 µs).
// r5 (split-K: +128MB partial traffic > gemm gain), r6 (deep vmcnt(6)
// staging: null), r7 (FFN2@BN=256 half-machine: null AND rule-#19 codegen
// perturbation slowed the untouched FFN1 93->135 µs) are all REVERTED.
// Do not alter the instantiation set {<3,256>,<4,128>,<2,256>,<5,128>}
// without re-measuring FFN1 — co-compiled instantiations share codegen
// context (rule #19, observed here at -45%).
//  A: MxK row-major bf16.  B: NxK row-major bf16 (B^T given).
//  BM=256, BK=64, 512 threads = 8 waves (2M x 4N). Per-wave out 128 x BN/4.
//  LDS per matrix: [2 dbuf][2 kh][rows][32 elems] (64B rows), double-buffered.
//  T1: bijective XCD-chunk swizzle — blocks sharing an A-panel land on the
//      same XCD L2 (fetch 282->82MB on PV gemm, r2). nwg mult of 8 always.
//  T2: st_16x32 swizzle — linear global_load_lds dest, source k-chunk XOR'd
//      by (row&8)?2:0, ds_read applies the same XOR. (rule #21: both sides)
//  T3/T4: counted vmcnt at the K-tile boundary only — never 0 mid-loop.
//  T5: setprio(1) around each MFMA cluster.
//  BN=256: 4 phases/K-tile, 16-MFMA clusters, vmcnt(4). FFN1: 93.0 µs,
//      739 TF = 87% of the shape-matched external reference (m248 848 TF
//      @256², K=1024).
//  BN=128: 2 phases/K-tile, 16-MFMA clusters, vmcnt(2) (r2->r4 fix: merged
//      phases halve barriers 8->3/K-tile, double cluster size; ~500 TF).
//  Swapped-operand MFMA: mfma(bfr, afr) -> lane holds row(l16) x 4 cols(quad).
//  EPI: 2 = +bias, GELU, bf16 out
//       3 = *scale + mask[batch][col], bf16 out       (QK^T scores)
//       4 = +resid[batch], fp32 out                   (PV: x + attn)
//       5 = +bias +resid, fp32 out                    (FFN2: h + ffn)
//  M mult of 256; N mult of BN; K mult of 128.
// ---------------------------------------------------------------------------
template<int EPI, int BN>
__global__ __launch_bounds__(512, 2) void gemm8p(
    const unsigned short* __restrict__ A, const unsigned short* __restrict__ B,
    const float* __restrict__ bias, const float* __restrict__ resid,
    void* __restrict__ Cptr,
    int M, int N, int K, long sA, long sB, long sC, long sBias, float scale)
{
    static_assert(BN == 256 || BN == 128, "BN must be 256 or 128");
    constexpr int WC = BN / 4;    // per-wave col span: 64 or 32
    constexpr int NT = WC / 16;   // n-tiles per wave: 4 or 2
    constexpr int NH = NT / 2;    // n-tiles per half-group: 2 or 1

    __shared__ alignas(16) unsigned short lds_a[2][2][256 * 32]; // 64 KB
    __shared__ alignas(16) unsigned short lds_b[2][2][BN * 32];  // 64/32 KB

    const int tid  = threadIdx.x;
    const int lane = tid & 63;
    const int wave = tid >> 6;         // 0..7
    const int quad = lane >> 4;
    const int l16  = lane & 15;
    const int wm = wave >> 2;          // 0..1  (128-row half)
    const int wn = wave & 3;           // 0..3  (WC-col slice)

    // ---- T1: XCD-chunk swizzle (nwg % 8 == 0 for all our grids) ----
    const int nwg = gridDim.x * gridDim.y * gridDim.z;
    int lin = blockIdx.x + gridDim.x * (blockIdx.y + gridDim.y * blockIdx.z);
    if ((nwg & 7) == 0) lin = (lin & 7) * (nwg >> 3) + (lin >> 3);
    const int bx = lin % gridDim.x;
    const int byz = lin / gridDim.x;
    const int by = byz % gridDim.y;
    const int bz = byz / gridDim.y;

    const int tile_m = by * 256;
    const int tile_n = bx * BN;
    const int batch  = bz;

    const unsigned short* Ab = A + (size_t)batch * sA;
    const unsigned short* Bb = B + (size_t)batch * sB;

    // staging: 512 threads x 16B = 8KB/inst = one [128 rows][32 elems] region.
    // LDS dest linear (tid*16B); global source k-chunk pre-swizzled.
    const int srow = tid >> 2;                                  // 0..127
    const int scs  = ((tid & 3) ^ ((tid & 32) ? 2 : 0)) * 8;    // swz chunk
    const unsigned short* gA = Ab + (size_t)(tile_m + srow) * K + scs;
    const unsigned short* gB = Bb + (size_t)(tile_n + srow) * K + scs;
    const int ldst = tid * 8;                                   // elems

    // fragment reads: row = (wm*128|wn*WC) + tile*16 + l16; row&8 == l16&8
    const int kcs   = (quad * 8) ^ ((l16 & 8) << 1);            // swz k-off
    const int abase = (wm * 128 + l16) * 32 + kcs;
    const int bbase = (wn * WC  + l16) * 32 + kcs;

    floatx4 acc[8][NT];
    const floatx4 zero = {0.f, 0.f, 0.f, 0.f};
#pragma unroll
    for (int i = 0; i < 8; i++)
#pragma unroll
        for (int j = 0; j < NT; j++) acc[i][j] = zero;

    auto stageA = [&](int buf, int h, int k0) {   // h = 128-row half
        const unsigned short* s = gA + (size_t)h * 128 * K + k0;
        gl_lds16(s,      &lds_a[buf][0][h * 4096 + ldst]);
        gl_lds16(s + 32, &lds_a[buf][1][h * 4096 + ldst]);
    };
    auto stageB = [&](int buf, int h, int k0) {
        const unsigned short* s = gB + (size_t)h * 128 * K + k0;
        gl_lds16(s,      &lds_b[buf][0][h * 4096 + ldst]);
        gl_lds16(s + 32, &lds_b[buf][1][h * 4096 + ldst]);
    };

    const int nt = K >> 6;

    // ---- prologue: tile0 fully + tile1's B (steady-state invariant) ----
    stageA(0, 0, 0); stageA(0, 1, 0);
    stageB(0, 0, 0);
    if constexpr (BN == 256) stageB(0, 1, 0);
    if (nt > 1) {
        stageB(1, 0, 64);
        if constexpr (BN == 256) stageB(1, 1, 64);
        if constexpr (BN == 256) { asm volatile("s_waitcnt vmcnt(4)" ::: "memory"); }
        else                     { asm volatile("s_waitcnt vmcnt(2)" ::: "memory"); }
    } else {
        asm volatile("s_waitcnt vmcnt(0)" ::: "memory");
    }
    __builtin_amdgcn_s_barrier(); CFENCE;

    int cur = 0;

    if constexpr (BN == 128) {
        // ================= 2-phase loop, 16-MFMA clusters =================
        for (int t = 0; t < nt; ++t) {
            const int k0 = t * 64;
            short8 afr[4][2], bfr[2][2];

            // ---- P1: read A rows q1 + ALL B ; stage A(t+1) ----
#pragma unroll
            for (int i = 0; i < 4; i++)
#pragma unroll
                for (int kh = 0; kh < 2; kh++)
                    afr[i][kh] = *(const short8*)&lds_a[cur][kh][abase + i * 512];
#pragma unroll
            for (int j = 0; j < 2; j++)
#pragma unroll
                for (int kh = 0; kh < 2; kh++)
                    bfr[j][kh] = *(const short8*)&lds_b[cur][kh][bbase + j * 512];
            if (t + 1 < nt) { stageA(cur ^ 1, 0, k0 + 64); stageA(cur ^ 1, 1, k0 + 64); }
            CFENCE; __builtin_amdgcn_s_barrier(); CFENCE;
            __builtin_amdgcn_s_setprio(1);
#pragma unroll
            for (int i = 0; i < 4; i++)
#pragma unroll
                for (int j = 0; j < 2; j++)
#pragma unroll
                    for (int kh = 0; kh < 2; kh++)
                        acc[i][j] = __builtin_amdgcn_mfma_f32_16x16x32_bf16(
                            bfr[j][kh], afr[i][kh], acc[i][j], 0, 0, 0);
            __builtin_amdgcn_s_setprio(0);
            // end-P1 barrier: all waves' B reads complete -> B buf half dead
            CFENCE; __builtin_amdgcn_s_barrier(); CFENCE;

            // ---- P2: read A rows q2 ; stage B(t+2) over dead half ----
#pragma unroll
            for (int i = 0; i < 4; i++)
#pragma unroll
                for (int kh = 0; kh < 2; kh++)
                    afr[i][kh] = *(const short8*)&lds_a[cur][kh][abase + (4 + i) * 512];
            if (t + 2 < nt) stageB(cur, 0, k0 + 128);
            __builtin_amdgcn_s_setprio(1);
#pragma unroll
            for (int i = 0; i < 4; i++)
#pragma unroll
                for (int j = 0; j < 2; j++)
#pragma unroll
                    for (int kh = 0; kh < 2; kh++)
                        acc[4 + i][j] = __builtin_amdgcn_mfma_f32_16x16x32_bf16(
                            bfr[j][kh], afr[i][kh], acc[4 + i][j], 0, 0, 0);
            __builtin_amdgcn_s_setprio(0);
            // K-tile boundary: outstanding = A(t+1)x4 + B(t+2)x2 -> vmcnt(2)
            if (t + 3 <= nt) {
                asm volatile("s_waitcnt vmcnt(2)" ::: "memory");
                __builtin_amdgcn_s_barrier(); CFENCE;
            } else if (t + 2 == nt) {
                asm volatile("s_waitcnt vmcnt(0)" ::: "memory");
                __builtin_amdgcn_s_barrier(); CFENCE;
            }
            cur ^= 1;
        }
    } else {
        // ================= 4-phase loop (m201 geometry) =================
        for (int t = 0; t < nt; ++t) {
            const int k0 = t * 64;
            short8 afr[4][2], bfrA[NH][2], bfrB[NH][2];

            // ========== P1: read A0 + B0 ; stage A(t+1, lo) ==========
#pragma unroll
            for (int i = 0; i < 4; i++)
#pragma unroll
                for (int kh = 0; kh < 2; kh++)
                    afr[i][kh] = *(const short8*)&lds_a[cur][kh][abase + i * 512];
#pragma unroll
            for (int j = 0; j < NH; j++)
#pragma unroll
                for (int kh = 0; kh < 2; kh++)
                    bfrA[j][kh] = *(const short8*)&lds_b[cur][kh][bbase + j * 512];
            if (t + 1 < nt) stageA(cur ^ 1, 0, k0 + 64);
            CFENCE; __builtin_amdgcn_s_barrier(); CFENCE;
            __builtin_amdgcn_s_setprio(1);
#pragma unroll
            for (int i = 0; i < 4; i++)
#pragma unroll
                for (int j = 0; j < NH; j++)
#pragma unroll
                    for (int kh = 0; kh < 2; kh++)
                        acc[i][j] = __builtin_amdgcn_mfma_f32_16x16x32_bf16(
                            bfrA[j][kh], afr[i][kh], acc[i][j], 0, 0, 0);
            __builtin_amdgcn_s_setprio(0);
            CFENCE; __builtin_amdgcn_s_barrier(); CFENCE;

            // ========== P2: read B1 ; stage A(t+1, hi) ==========
#pragma unroll
            for (int j = 0; j < NH; j++)
#pragma unroll
                for (int kh = 0; kh < 2; kh++)
                    bfrB[j][kh] = *(const short8*)&lds_b[cur][kh][bbase + (NH + j) * 512];
            if (t + 1 < nt) stageA(cur ^ 1, 1, k0 + 64);
            CFENCE; __builtin_amdgcn_s_barrier(); CFENCE;
            __builtin_amdgcn_s_setprio(1);
#pragma unroll
            for (int i = 0; i < 4; i++)
#pragma unroll
                for (int j = 0; j < NH; j++)
#pragma unroll
                    for (int kh = 0; kh < 2; kh++)
                        acc[i][NH + j] = __builtin_amdgcn_mfma_f32_16x16x32_bf16(
                            bfrB[j][kh], afr[i][kh], acc[i][NH + j], 0, 0, 0);
            __builtin_amdgcn_s_setprio(0);
            CFENCE; __builtin_amdgcn_s_barrier(); CFENCE;

            // ========== P3: read A1 ; stage B(t+2, lo) ==========
#pragma unroll
            for (int i = 0; i < 4; i++)
#pragma unroll
                for (int kh = 0; kh < 2; kh++)
                    afr[i][kh] = *(const short8*)&lds_a[cur][kh][abase + (4 + i) * 512];
            if (t + 2 < nt) stageB(cur, 0, k0 + 128);
            CFENCE; __builtin_amdgcn_s_barrier(); CFENCE;
            __builtin_amdgcn_s_setprio(1);
#pragma unroll
            for (int i = 0; i < 4; i++)
#pragma unroll
                for (int j = 0; j < NH; j++)
#pragma unroll
                    for (int kh = 0; kh < 2; kh++)
                        acc[4 + i][NH + j] = __builtin_amdgcn_mfma_f32_16x16x32_bf16(
                            bfrB[j][kh], afr[i][kh], acc[4 + i][NH + j], 0, 0, 0);
            __builtin_amdgcn_s_setprio(0);
            CFENCE; __builtin_amdgcn_s_barrier(); CFENCE;

            // ========== P4: stage B(t+2, hi) ; MFMA from regs ; boundary ==
            if (t + 2 < nt) stageB(cur, 1, k0 + 128);
            __builtin_amdgcn_s_setprio(1);
#pragma unroll
            for (int i = 0; i < 4; i++)
#pragma unroll
                for (int j = 0; j < NH; j++)
#pragma unroll
                    for (int kh = 0; kh < 2; kh++)
                        acc[4 + i][j] = __builtin_amdgcn_mfma_f32_16x16x32_bf16(
                            bfrA[j][kh], afr[i][kh], acc[4 + i][j], 0, 0, 0);
            __builtin_amdgcn_s_setprio(0);
            if (t + 3 <= nt) {
                asm volatile("s_waitcnt vmcnt(4)" ::: "memory");
                __builtin_amdgcn_s_barrier(); CFENCE;
            } else if (t + 2 == nt) {
                asm volatile("s_waitcnt vmcnt(0)" ::: "memory");
                __builtin_amdgcn_s_barrier(); CFENCE;
            }
            cur ^= 1;
        }
    }

    // ---- epilogue: per frag, lane holds row (l16) x 4 consecutive cols ----
#pragma unroll
    for (int i = 0; i < 8; i++) {
        const int row = tile_m + wm * 128 + i * 16 + l16;
#pragma unroll
        for (int j = 0; j < NT; j++) {
            const int colb = tile_n + wn * WC + j * 16 + quad * 4;
            float v[4];
#pragma unroll
            for (int r = 0; r < 4; r++) v[r] = acc[i][j][r];

            if (EPI == 3) {
                float4 mv = *(const float4*)&bias[(size_t)batch * sBias + colb];
                v[0] = v[0] * scale + mv.x;  v[1] = v[1] * scale + mv.y;
                v[2] = v[2] * scale + mv.z;  v[3] = v[3] * scale + mv.w;
            }
            if (EPI == 2 || EPI == 5) {
                float4 bv = *(const float4*)&bias[colb];
                v[0] += bv.x; v[1] += bv.y; v[2] += bv.z; v[3] += bv.w;
            }
            if (EPI == 2) {
#pragma unroll
                for (int r = 0; r < 4; r++) v[r] = gelu_f(v[r]);
            }
            if (EPI == 4 || EPI == 5) {
                float4 rv = *(const float4*)&resid[(size_t)batch * sC +
                                                   (size_t)row * N + colb];
                v[0] += rv.x; v[1] += rv.y; v[2] += rv.z; v[3] += rv.w;
            }

            if (EPI == 2 || EPI == 3) {
                unsigned short* C = (unsigned short*)Cptr + (size_t)batch * sC;
                ushort4 h4;
                h4.x = f2bf(v[0]); h4.y = f2bf(v[1]);
                h4.z = f2bf(v[2]); h4.w = f2bf(v[3]);
                *(ushort4*)(C + (size_t)row * N + colb) = h4;
            } else {
                float* C = (float*)Cptr + (size_t)batch * sC;
                float4 f4 = {v[0], v[1], v[2], v[3]};
                *(float4*)(C + (size_t)row * N + colb) = f4;
            }
        }
    }
}

// ---------------------------------------------------------------------------
// x prep: read x [S,D] fp32 once -> xb [S,D] bf16 AND xTb [D,S] bf16.
// ---------------------------------------------------------------------------
__global__ __launch_bounds__(256) void x_prep_kernel(
    const float* __restrict__ in, unsigned short* __restrict__ straight,
    unsigned short* __restrict__ transposed, int R, int C, long sIn)
{
    __shared__ float tile[32][33];
    const int tc = blockIdx.x * 32, tr = blockIdx.y * 32;
    const float* src = in + (size_t)blockIdx.z * sIn;
    unsigned short* dstS = straight   + (size_t)blockIdx.z * sIn;
    unsigned short* dstT = transposed + (size_t)blockIdx.z * sIn;
    const int tx = threadIdx.x & 31, ty = threadIdx.x >> 5;
#pragma unroll
    for (int i = 0; i < 4; i++) {
        float val = src[(size_t)(tr + ty + i * 8) * C + tc + tx];
        tile[ty + i * 8][tx] = val;
        dstS[(size_t)(tr + ty + i * 8) * C + tc + tx] = f2bf(val);
    }
    __syncthreads();
#pragma unroll
    for (int i = 0; i < 4; i++)
        dstT[(size_t)(tc + ty + i * 8) * R + tr + tx] = f2bf(tile[tx][ty + i * 8]);
}

// ---------------------------------------------------------------------------
__global__ __launch_bounds__(256) void transpose_cvt_kernel(
    const float* __restrict__ in, unsigned short* __restrict__ out, int R, int C)
{
    __shared__ float tile[32][33];
    const int tc = blockIdx.x * 32, tr = blockIdx.y * 32;
    const int tx = threadIdx.x & 31, ty = threadIdx.x >> 5;
#pragma unroll
    for (int i = 0; i < 4; i++)
        tile[ty + i * 8][tx] = in[(size_t)(tr + ty + i * 8) * C + tc + tx];
    __syncthreads();
#pragma unroll
    for (int i = 0; i < 4; i++)
        out[(size_t)(tc + ty + i * 8) * R + tr + tx] = f2bf(tile[tx][ty + i * 8]);
}

// ---------------------------------------------------------------------------
// Pure row softmax over S=2048: bf16 in (scale+mask pre-applied) -> bf16 out.
// ---------------------------------------------------------------------------
__global__ __launch_bounds__(256) void softmax_bf16_kernel(
    const unsigned short* __restrict__ scores, unsigned short* __restrict__ probs,
    int S)
{
    __shared__ float red[4];
    const int row = blockIdx.x;
    const unsigned short* p = scores + (size_t)row * S;
    unsigned short* pr      = probs  + (size_t)row * S;
    const int tid  = threadIdx.x;
    const int lane = tid & 63;
    const int wav  = tid >> 6;

    uint4 raw = *(const uint4*)(p + tid * 8);   // 8 bf16
    float v[8];
    v[0] = __uint_as_float(raw.x << 16); v[1] = __uint_as_float(raw.x & 0xffff0000u);
    v[2] = __uint_as_float(raw.y << 16); v[3] = __uint_as_float(raw.y & 0xffff0000u);
    v[4] = __uint_as_float(raw.z << 16); v[5] = __uint_as_float(raw.z & 0xffff0000u);
    v[6] = __uint_as_float(raw.w << 16); v[7] = __uint_as_float(raw.w & 0xffff0000u);

    float mx = v[0];
#pragma unroll
    for (int k = 1; k < 8; k++) mx = fmaxf(mx, v[k]);
#pragma unroll
    for (int off = 32; off > 0; off >>= 1) mx = fmaxf(mx, __shfl_down(mx, off));
    if (lane == 0) red[wav] = mx;
    __syncthreads();
    mx = fmaxf(fmaxf(red[0], red[1]), fmaxf(red[2], red[3]));
    __syncthreads();

    float s = 0.f;
#pragma unroll
    for (int k = 0; k < 8; k++) { v[k] = __expf(v[k] - mx); s += v[k]; }
#pragma unroll
    for (int off = 32; off > 0; off >>= 1) s += __shfl_down(s, off);
    if (lane == 0) red[wav] = s;
    __syncthreads();
    s = red[0] + red[1] + red[2] + red[3];
    float inv = 1.0f / s;

    uint4 o;
    o.x = (unsigned)f2bf(v[0] * inv) | ((unsigned)f2bf(v[1] * inv) << 16);
    o.y = (unsigned)f2bf(v[2] * inv) | ((unsigned)f2bf(v[3] * inv) << 16);
    o.z = (unsigned)f2bf(v[4] * inv) | ((unsigned)f2bf(v[5] * inv) << 16);
    o.w = (unsigned)f2bf(v[6] * inv) | ((unsigned)f2bf(v[7] * inv) << 16);
    *(uint4*)(pr + tid * 8) = o;
}

// ---------------------------------------------------------------------------
// out_row = LayerNorm(X_row)*g + b.  D = 1024. In-place safe (out == X).
// ---------------------------------------------------------------------------
template<int WRITE_BF16>
__global__ __launch_bounds__(256) void ln_kernel(
    const float* __restrict__ X,
    const float* __restrict__ g, const float* __restrict__ bta,
    float* __restrict__ out, unsigned short* __restrict__ out16, int D)
{
    __shared__ float red[8];
    const int row = blockIdx.x;
    const float* x = X + (size_t)row * D;
    const int tid  = threadIdx.x;
    const int lane = tid & 63;
    const int wav  = tid >> 6;

    float4 a = *(const float4*)(x + tid * 4);
    float v0 = a.x, v1 = a.y, v2 = a.z, v3 = a.w;

    float s1 = v0 + v1 + v2 + v3;
    float s2 = v0 * v0 + v1 * v1 + v2 * v2 + v3 * v3;
#pragma unroll
    for (int off = 32; off > 0; off >>= 1) {
        s1 += __shfl_down(s1, off);
        s2 += __shfl_down(s2, off);
    }
    if (lane == 0) { red[wav] = s1; red[4 + wav] = s2; }
    __syncthreads();
    s1 = red[0] + red[1] + red[2] + red[3];
    s2 = red[4] + red[5] + red[6] + red[7];
    const float mu  = s1 / (float)D;
    const float var = s2 / (float)D - mu * mu;
    const float rs  = rsqrtf(var + LN_EPS);

    float4 gg = *(const float4*)(g + tid * 4);
    float4 bb = *(const float4*)(bta + tid * 4);
    float4 r;
    r.x = (v0 - mu) * rs * gg.x + bb.x;
    r.y = (v1 - mu) * rs * gg.y + bb.y;
    r.z = (v2 - mu) * rs * gg.z + bb.z;
    r.w = (v3 - mu) * rs * gg.w + bb.w;
    *(float4*)(out + (size_t)row * D + tid * 4) = r;
    if (WRITE_BF16) {
        ushort4 h;
        h.x = f2bf(r.x); h.y = f2bf(r.y); h.z = f2bf(r.z); h.w = f2bf(r.w);
        *(ushort4*)(out16 + (size_t)row * D + tid * 4) = h;
    }
}

// ---------------------------------------------------------------------------
extern "C" void kernel_launch(void* const* d_in, const int* in_sizes, int n_in,
                              void* d_out, int out_size, void* d_ws, size_t ws_size,
                              hipStream_t stream) {
    (void)in_sizes; (void)n_in; (void)out_size; (void)ws_size;
    const float* x    = (const float*)d_in[0];
    const float* mask = (const float*)d_in[1];
    const float* w1   = (const float*)d_in[2];
    const float* b1   = (const float*)d_in[3];
    const float* w2   = (const float*)d_in[4];
    const float* b2   = (const float*)d_in[5];
    const float* ln1g = (const float*)d_in[6];
    const float* ln1b = (const float*)d_in[7];
    const float* ln2g = (const float*)d_in[8];
    const float* ln2b = (const float*)d_in[9];
    float* out = (float*)d_out;

    const int B = 4, S = 2048, D = 1024, DFF = 4096;
    const size_t MB = 1024 * 1024;

    // ws (128 MiB):
    //  [0,32M):   scoresb bf16 (1-2)         } act bf16 [0,64M) (5-6)
    //  [32,64M):  xb bf16 [32,48M) (prep-1), then probs bf16 (2-3)
    //  [64,96M):  hbuf fp32 = h (3-6)
    //  [96,112M): hb16 bf16 (4-5)
    //  [112,120M): w1T   [120,128M): w2T
    // d_out (32 MiB): xTb [0,16M) (prep-3); then fsum fp32 = h+ffn (6-7), LN in place.
    char* ws = (char*)d_ws;
    unsigned short* scoresb = (unsigned short*)ws;
    unsigned short* act     = (unsigned short*)ws;
    unsigned short* xb      = (unsigned short*)(ws + 32 * MB);
    unsigned short* probs   = (unsigned short*)(ws + 32 * MB);
    float*          hbuf    = (float*)(ws + 64 * MB);
    unsigned short* hb16    = (unsigned short*)(ws + 96 * MB);
    unsigned short* w1T     = (unsigned short*)(ws + 112 * MB);
    unsigned short* w2T     = (unsigned short*)(ws + 120 * MB);
    unsigned short* xTb     = (unsigned short*)d_out;
    float*          fsum    = (float*)d_out;

    // --- prep ---
    x_prep_kernel<<<dim3(D / 32, S / 32, B), 256, 0, stream>>>(
        x, xb, xTb, S, D, (long)S * D);
    transpose_cvt_kernel<<<dim3(DFF / 32, D / 32, 1), 256, 0, stream>>>(w1, w1T, D, DFF);
    transpose_cvt_kernel<<<dim3(D / 32, DFF / 32, 1), 256, 0, stream>>>(w2, w2T, DFF, D);

    // 1. scoresb[b] = (xb[b] @ xb[b]^T)*scale + mask  -> bf16   (256 blocks)
    hipLaunchKernelGGL((gemm8p<3, 256>), dim3(S / 256, S / 256, B), dim3(512), 0, stream,
                       xb, xb, mask, (const float*)nullptr, (void*)scoresb,
                       S, S, D, (long)S * D, (long)S * D, (long)S * S, (long)S, 0.03125f);
    // 2. probs = softmax(scoresb) -> bf16
    softmax_bf16_kernel<<<B * S, 256, 0, stream>>>(scoresb, probs, S);
    // 3. hbuf[b] = x[b] + probs[b] @ xTb[b]^T  -> fp32          (256 blocks)
    hipLaunchKernelGGL((gemm8p<4, 128>), dim3(D / 128, S / 256, B), dim3(512), 0, stream,
                       probs, xTb, (const float*)nullptr, x, (void*)hbuf,
                       S, D, S, (long)S * S, (long)D * S, (long)S * D, 0L, 0.f);
    // 4. h = LN(hbuf) in place + hb16 bf16
    hipLaunchKernelGGL((ln_kernel<1>), dim3(B * S), dim3(256), 0, stream,
                       hbuf, ln1g, ln1b, hbuf, hb16, D);
    // 5. act = gelu(h @ w1 + b1) -> bf16                        (512 blocks)
    hipLaunchKernelGGL((gemm8p<2, 256>), dim3(DFF / 256, (B * S) / 256, 1), dim3(512), 0, stream,
                       hb16, w1T, b1, (const float*)nullptr, (void*)act,
                       B * S, DFF, D, 0L, 0L, 0L, 0L, 0.f);
    // 6. fsum = h + act @ w2 + b2 -> fp32 (into d_out)          (256 blocks)
    hipLaunchKernelGGL((gemm8p<5, 128>), dim3(D / 128, (B * S) / 256, 1), dim3(512), 0, stream,
                       act, w2T, b2, hbuf, (void*)fsum,
                       B * S, D, DFF, 0L, 0L, 0L, 0L, 0.f);
    // 7. out = LN(fsum) in place
    hipLaunchKernelGGL((ln_kernel<0>), dim3(B * S), dim3(256), 0, stream,
                       fsum, ln2g, ln2b, out, (unsigned short*)nullptr, D);
}